// Round 1
// baseline (329.916 us; speedup 1.0000x reference)
//
#include <hip/hip_runtime.h>
#include <stdint.h>

typedef unsigned short u16;
typedef __bf16 bf16x8 __attribute__((ext_vector_type(8)));
typedef float f32x4 __attribute__((ext_vector_type(4)));

#define KDIM   768
#define MP     6400      // padded token-row count (50 * 128)
#define MREAL  6304      // 32 * 197
#define SLOT   ((size_t)MP * KDIM)
#define WSZ    ((size_t)KDIM * KDIM)
#define QSCALE 0.125f    // 1/sqrt(64)

struct Ptr9 { const float* p[9]; };
struct Ptr7 { const float* p[7]; };

__device__ __forceinline__ u16 f2b(float f) {
  uint32_t x = __float_as_uint(f);
  x += 0x7FFFu + ((x >> 16) & 1u);   // RNE
  return (u16)(x >> 16);
}

__device__ __forceinline__ void async16(const void* g, void* l) {
  __builtin_amdgcn_global_load_lds(
      (__attribute__((address_space(1))) void*)(uintptr_t)g,
      (__attribute__((address_space(3))) void*)l, 16, 0, 0);
}

// ---------------- fp32 -> bf16 conversion (x + 8 weight matrices) -------------
__global__ __launch_bounds__(256) void k_convert(Ptr9 src, u16* __restrict__ xb,
                                                 u16* __restrict__ wall) {
  const int XN4 = MREAL * KDIM / 4;     // 1,210,368
  const int WN4 = (int)(WSZ / 4);       // 147,456
  const int total = XN4 + 8 * WN4;
  for (int i = blockIdx.x * blockDim.x + threadIdx.x; i < total;
       i += gridDim.x * blockDim.x) {
    const float4* sp; ushort4* dp; int off;
    if (i < XN4) { sp = (const float4*)src.p[0]; dp = (ushort4*)xb; off = i; }
    else {
      int t = i - XN4; int slot = t / WN4; off = t - slot * WN4;
      sp = (const float4*)src.p[1 + slot];
      dp = (ushort4*)(wall + (size_t)slot * WSZ);
    }
    float4 v = sp[off];
    ushort4 u;
    u.x = f2b(v.x); u.y = f2b(v.y); u.z = f2b(v.z); u.w = f2b(v.w);
    dp[off] = u;
  }
}

// ---------------- bf16 MFMA GEMM: C = A @ W^T + bias -------------------------
// A: [MP][768] bf16 (k-contiguous). W: per-z [768][768] bf16 (torch Linear
// weight layout, k-contiguous rows). Epilogue: (acc + bias) * scale,
// stored bf16 to outb (z slots) or fp32 to outf (row-guarded).
__global__ __launch_bounds__(256) void k_gemm(const u16* __restrict__ A,
                                              const u16* __restrict__ W,
                                              Ptr7 bias,
                                              u16* __restrict__ outb,
                                              float* __restrict__ outf,
                                              float scale0, int guard) {
  __shared__ u16 As[128 * 32];
  __shared__ u16 Bs[128 * 32];
  const int tid = threadIdx.x;
  const int w = tid >> 6, lane = tid & 63;
  const int li = lane & 15, g = lane >> 4;
  const int brow = blockIdx.x, bcol = blockIdx.y, z = blockIdx.z;
  const u16* Wz = W + (size_t)z * WSZ;
  const float* bz = bias.p[z];
  const int wr = (w >> 1) * 64, wc = (w & 1) * 64;
  f32x4 acc[4][4] = {};

  for (int k0 = 0; k0 < KDIM; k0 += 32) {
    __syncthreads();               // previous tile's readers done
#pragma unroll
    for (int c = 0; c < 2; ++c) {
      int cbase = (c * 4 + w) * 64;           // wave-uniform chunk base
      int chunk = cbase + lane;               // this lane's 16B chunk
      int row = chunk >> 2, kg = chunk & 3;   // 4 chunks per 32-elem row
      async16(A  + (size_t)(brow * 128 + row) * KDIM + k0 + kg * 8,
              (char*)As + cbase * 16);
      async16(Wz + (size_t)(bcol * 128 + row) * KDIM + k0 + kg * 8,
              (char*)Bs + cbase * 16);
    }
    asm volatile("s_waitcnt vmcnt(0)" ::: "memory");
    __syncthreads();

    bf16x8 af[4], bfr[4];
#pragma unroll
    for (int i = 0; i < 4; ++i) {
      af[i]  = *(const bf16x8*)(As + (wr + i * 16 + li) * 32 + g * 8);
      bfr[i] = *(const bf16x8*)(Bs + (wc + i * 16 + li) * 32 + g * 8);
    }
#pragma unroll
    for (int i = 0; i < 4; ++i)
#pragma unroll
      for (int j = 0; j < 4; ++j)
        acc[i][j] = __builtin_amdgcn_mfma_f32_16x16x32_bf16(af[i], bfr[j],
                                                            acc[i][j], 0, 0, 0);
  }

  const float scz = (z == 0) ? scale0 : 1.0f;
  if (outf == nullptr) {
    u16* O = outb + (size_t)z * SLOT;
#pragma unroll
    for (int j = 0; j < 4; ++j) {
      int col = bcol * 128 + wc + j * 16 + li;
      float bsv = bz[col];
#pragma unroll
      for (int i = 0; i < 4; ++i) {
        int row = brow * 128 + wr + i * 16 + g * 4;
#pragma unroll
        for (int r = 0; r < 4; ++r)
          O[(size_t)(row + r) * KDIM + col] = f2b((acc[i][j][r] + bsv) * scz);
      }
    }
  } else {
#pragma unroll
    for (int j = 0; j < 4; ++j) {
      int col = bcol * 128 + wc + j * 16 + li;
      float bsv = bz[col];
#pragma unroll
      for (int i = 0; i < 4; ++i) {
        int row = brow * 128 + wr + i * 16 + g * 4;
#pragma unroll
        for (int r = 0; r < 4; ++r)
          if (row + r < guard)
            outf[(size_t)(row + r) * KDIM + col] = acc[i][j][r] + bsv;
      }
    }
  }
}

// ---------------- fused 5-mask attention -------------------------------------
// Block = (row-group rg, head h, batch b), 256 threads = 4 waves.
// qkv slots: 0=q (pre-scaled), 1..5 = kA..kE, 6 = v. All [MP][768] bf16.
__global__ __launch_bounds__(256) void k_attn(const u16* __restrict__ qkv,
                                              u16* __restrict__ att) {
  __shared__ u16 VT[64][232];       // V^T, padded cols zeroed
  __shared__ u16 P[4][16][232];     // per-wave softmax tile
  const int tid = threadIdx.x;
  const int w = tid >> 6, lane = tid & 63;
  const int li = lane & 15, g = lane >> 4;
  const int rg = blockIdx.x, h = blockIdx.y, b = blockIdx.z;
  const size_t rowbase = (size_t)b * 197;
  const int cb = h * 64;
  const u16* Q = qkv;
  const u16* V = qkv + 6 * SLOT;

  // stage V^T (coalesced global reads; pad j>=197 with zeros)
  for (int e = tid; e < 64 * 224; e += 256) {
    int j = e >> 6, d = e & 63;
    u16 val = 0;
    if (j < 197) val = V[(rowbase + j) * KDIM + cb + d];
    VT[d][j] = val;
  }
  // zero P pad cols 208..223 (wave-local; never rewritten)
  for (int e = lane; e < 256; e += 64) P[w][e >> 4][208 + (e & 15)] = 0;
  __syncthreads();

  for (int it = 0; it < 2; ++it) {
    int rt;
    if (rg == 0) rt = it * 4 + w;                       // tiles 0..7
    else rt = (it == 0) ? (8 + w) : ((w == 0) ? 12 : 99); // tiles 8..12
    if (rt > 12) continue;

    const size_t qrow = rowbase + rt * 16 + li;
    bf16x8 qa0 = *(const bf16x8*)(Q + qrow * KDIM + cb + g * 8);
    bf16x8 qa1 = *(const bf16x8*)(Q + qrow * KDIM + cb + 32 + g * 8);
    f32x4 oacc[4] = {};

    for (int m = 0; m < 5; ++m) {
      const u16* K = qkv + (size_t)(1 + m) * SLOT;
      f32x4 s[13];
#pragma unroll
      for (int t = 0; t < 13; ++t) {
        const size_t krow = rowbase + t * 16 + li;
        bf16x8 kb0 = *(const bf16x8*)(K + krow * KDIM + cb + g * 8);
        bf16x8 kb1 = *(const bf16x8*)(K + krow * KDIM + cb + 32 + g * 8);
        f32x4 zz = {};
        zz = __builtin_amdgcn_mfma_f32_16x16x32_bf16(qa0, kb0, zz, 0, 0, 0);
        zz = __builtin_amdgcn_mfma_f32_16x16x32_bf16(qa1, kb1, zz, 0, 0, 0);
        s[t] = zz;
      }
      // analytic mask; ADD -1e9 (reference semantics: fully-masked rows
      // reduce to plain softmax by shift-invariance). Pad cols j>=197 get
      // a hard overwrite so garbage/NaN K rows can never leak in.
#pragma unroll
      for (int t = 0; t < 13; ++t) {
        int j = t * 16 + li;
        int pj = j - 1;
        int rj = pj / 14, cj = pj % 14;
        bool jv = (j < 197);
#pragma unroll
        for (int r = 0; r < 4; ++r) {
          int i = rt * 16 + g * 4 + r;
          float sv = s[t][r];
          if (!jv) sv = -1e30f;
          else {
            int pi = i - 1;
            int ri = pi / 14, ci = pi % 14;
            bool mk;
            if (m == 0)      mk = ci < cj;    // left
            else if (m == 1) mk = ci > cj;    // right
            else if (m == 2) mk = ri < rj;    // up
            else if (m == 3) mk = ri > rj;    // down
            else             mk = (i == j);   // ident
            if (i == 0 || j == 0) mk = false; // CLS pad row/col
            if (!mk) sv -= 1e9f;
          }
          s[t][r] = sv;
        }
      }
      // row softmax: 13 regs/lane + 16-lane shuffle reduce, per reg-row r
#pragma unroll
      for (int r = 0; r < 4; ++r) {
        float mx = s[0][r];
#pragma unroll
        for (int t = 1; t < 13; ++t) mx = fmaxf(mx, s[t][r]);
        mx = fmaxf(mx, __shfl_xor(mx, 1));
        mx = fmaxf(mx, __shfl_xor(mx, 2));
        mx = fmaxf(mx, __shfl_xor(mx, 4));
        mx = fmaxf(mx, __shfl_xor(mx, 8));
        float sum = 0.f;
#pragma unroll
        for (int t = 0; t < 13; ++t) {
          float e_ = __expf(s[t][r] - mx);
          s[t][r] = e_;
          sum += e_;
        }
        sum += __shfl_xor(sum, 1);
        sum += __shfl_xor(sum, 2);
        sum += __shfl_xor(sum, 4);
        sum += __shfl_xor(sum, 8);
        float inv = 1.f / sum;
#pragma unroll
        for (int t = 0; t < 13; ++t)
          P[w][g * 4 + r][t * 16 + li] = f2b(s[t][r] * inv);
      }
      // PV: accumulate over masks into oacc
#pragma unroll
      for (int kt = 0; kt < 7; ++kt) {
        bf16x8 pa = *(const bf16x8*)(&P[w][li][kt * 32 + g * 8]);
#pragma unroll
        for (int dt = 0; dt < 4; ++dt) {
          bf16x8 vb = *(const bf16x8*)(&VT[dt * 16 + li][kt * 32 + g * 8]);
          oacc[dt] = __builtin_amdgcn_mfma_f32_16x16x32_bf16(pa, vb, oacc[dt],
                                                             0, 0, 0);
        }
      }
    }
    // store attention output (bf16, [token][h*64+d])
#pragma unroll
    for (int dt = 0; dt < 4; ++dt)
#pragma unroll
      for (int r = 0; r < 4; ++r) {
        int i = rt * 16 + g * 4 + r;
        if (i < 197)
          att[(rowbase + i) * KDIM + cb + dt * 16 + li] = f2b(oacc[dt][r]);
      }
  }
}

// -----------------------------------------------------------------------------
extern "C" void kernel_launch(void* const* d_in, const int* in_sizes, int n_in,
                              void* d_out, int out_size, void* d_ws, size_t ws_size,
                              hipStream_t stream) {
  (void)in_sizes; (void)n_in; (void)out_size; (void)ws_size;
  const float* x      = (const float*)d_in[0];
  const float* q_w    = (const float*)d_in[1];
  const float* q_b    = (const float*)d_in[2];
  const float* kA_w   = (const float*)d_in[3];
  const float* kA_b   = (const float*)d_in[4];
  const float* kB_w   = (const float*)d_in[5];
  const float* kB_b   = (const float*)d_in[6];
  const float* kC_w   = (const float*)d_in[7];
  const float* kC_b   = (const float*)d_in[8];
  const float* kD_w   = (const float*)d_in[9];
  const float* kD_b   = (const float*)d_in[10];
  const float* kE_w   = (const float*)d_in[11];
  const float* kE_b   = (const float*)d_in[12];
  const float* v_w    = (const float*)d_in[13];
  const float* v_b    = (const float*)d_in[14];
  const float* proj_w = (const float*)d_in[15];
  const float* proj_b = (const float*)d_in[16];
  float* out = (float*)d_out;

  // ws layout (bf16/u16 elements): [x_b | qkv(7) | w_all(8)] ; att aliases x_b
  u16* xb   = (u16*)d_ws;                 // SLOT
  u16* qkv  = xb + SLOT;                  // 7 * SLOT
  u16* wall = qkv + 7 * SLOT;             // 8 * WSZ
  u16* att  = xb;                         // reuse after gemm1 consumed x_b

  Ptr9 cs;
  cs.p[0] = x;    cs.p[1] = q_w;  cs.p[2] = kA_w; cs.p[3] = kB_w;
  cs.p[4] = kC_w; cs.p[5] = kD_w; cs.p[6] = kE_w; cs.p[7] = v_w;
  cs.p[8] = proj_w;
  k_convert<<<dim3(2048), dim3(256), 0, stream>>>(cs, xb, wall);

  Ptr7 b1;
  b1.p[0] = q_b;  b1.p[1] = kA_b; b1.p[2] = kB_b; b1.p[3] = kC_b;
  b1.p[4] = kD_b; b1.p[5] = kE_b; b1.p[6] = v_b;
  k_gemm<<<dim3(50, 6, 7), dim3(256), 0, stream>>>(xb, wall, b1, qkv, nullptr,
                                                   QSCALE, 0);

  k_attn<<<dim3(2, 12, 32), dim3(256), 0, stream>>>(qkv, att);

  Ptr7 b2;
  for (int i = 0; i < 7; ++i) b2.p[i] = proj_b;
  k_gemm<<<dim3(50, 6, 1), dim3(256), 0, stream>>>(att, wall + 7 * WSZ, b2,
                                                   nullptr, out, 1.0f, MREAL);
}

// Round 2
// 263.773 us; speedup vs baseline: 1.2508x; 1.2508x over previous
//
#include <hip/hip_runtime.h>
#include <stdint.h>

typedef unsigned short u16;
typedef __bf16 bf16x8 __attribute__((ext_vector_type(8)));
typedef float f32x4 __attribute__((ext_vector_type(4)));

#define KDIM   768
#define MP     6400      // padded token-row count (50 * 128)
#define MREAL  6304      // 32 * 197
#define SLOT   ((size_t)MP * KDIM)
#define WSZ    ((size_t)KDIM * KDIM)
#define QSCALE_L 0.18033688011112042f   // 0.125 * log2(e): QK^T lands in log2 domain
#define BIGL     1.4426950e9f           // 1e9 * log2(e)

struct Ptr9 { const float* p[9]; };
struct Ptr7 { const float* p[7]; };

__device__ __forceinline__ u16 f2b(float f) {
  uint32_t x = __float_as_uint(f);
  x += 0x7FFFu + ((x >> 16) & 1u);   // RNE
  return (u16)(x >> 16);
}

__device__ __forceinline__ void async16(const void* g, void* l) {
  __builtin_amdgcn_global_load_lds(
      (__attribute__((address_space(1))) void*)(uintptr_t)g,
      (__attribute__((address_space(3))) void*)l, 16, 0, 0);
}

// ---------------- fp32 -> bf16 conversion (x + 8 weight matrices) -------------
__global__ __launch_bounds__(256) void k_convert(Ptr9 src, u16* __restrict__ xb,
                                                 u16* __restrict__ wall) {
  const int XN4 = MREAL * KDIM / 4;
  const int WN4 = (int)(WSZ / 4);
  const int total = XN4 + 8 * WN4;
  for (int i = blockIdx.x * blockDim.x + threadIdx.x; i < total;
       i += gridDim.x * blockDim.x) {
    const float4* sp; ushort4* dp; int off;
    if (i < XN4) { sp = (const float4*)src.p[0]; dp = (ushort4*)xb; off = i; }
    else {
      int t = i - XN4; int slot = t / WN4; off = t - slot * WN4;
      sp = (const float4*)src.p[1 + slot];
      dp = (ushort4*)(wall + (size_t)slot * WSZ);
    }
    float4 v = sp[off];
    ushort4 u;
    u.x = f2b(v.x); u.y = f2b(v.y); u.z = f2b(v.z); u.w = f2b(v.w);
    dp[off] = u;
  }
}

// ---------------- bf16 MFMA GEMM: C = A @ W^T + bias -------------------------
__global__ __launch_bounds__(256) void k_gemm(const u16* __restrict__ A,
                                              const u16* __restrict__ W,
                                              Ptr7 bias,
                                              u16* __restrict__ outb,
                                              float* __restrict__ outf,
                                              float scale0, int guard) {
  __shared__ u16 As[128 * 32];
  __shared__ u16 Bs[128 * 32];
  const int tid = threadIdx.x;
  const int w = tid >> 6, lane = tid & 63;
  const int li = lane & 15, g = lane >> 4;
  const int brow = blockIdx.x, bcol = blockIdx.y, z = blockIdx.z;
  const u16* Wz = W + (size_t)z * WSZ;
  const float* bz = bias.p[z];
  const int wr = (w >> 1) * 64, wc = (w & 1) * 64;
  f32x4 acc[4][4] = {};

  for (int k0 = 0; k0 < KDIM; k0 += 32) {
    __syncthreads();
#pragma unroll
    for (int c = 0; c < 2; ++c) {
      int cbase = (c * 4 + w) * 64;
      int chunk = cbase + lane;
      int row = chunk >> 2, kg = chunk & 3;
      async16(A  + (size_t)(brow * 128 + row) * KDIM + k0 + kg * 8,
              (char*)As + cbase * 16);
      async16(Wz + (size_t)(bcol * 128 + row) * KDIM + k0 + kg * 8,
              (char*)Bs + cbase * 16);
    }
    asm volatile("s_waitcnt vmcnt(0)" ::: "memory");
    __syncthreads();

    bf16x8 af[4], bfr[4];
#pragma unroll
    for (int i = 0; i < 4; ++i) {
      af[i]  = *(const bf16x8*)(As + (wr + i * 16 + li) * 32 + g * 8);
      bfr[i] = *(const bf16x8*)(Bs + (wc + i * 16 + li) * 32 + g * 8);
    }
#pragma unroll
    for (int i = 0; i < 4; ++i)
#pragma unroll
      for (int j = 0; j < 4; ++j)
        acc[i][j] = __builtin_amdgcn_mfma_f32_16x16x32_bf16(af[i], bfr[j],
                                                            acc[i][j], 0, 0, 0);
  }

  const float scz = (z == 0) ? scale0 : 1.0f;
  if (outf == nullptr) {
    u16* O = outb + (size_t)z * SLOT;
#pragma unroll
    for (int j = 0; j < 4; ++j) {
      int col = bcol * 128 + wc + j * 16 + li;
      float bsv = bz[col];
#pragma unroll
      for (int i = 0; i < 4; ++i) {
        int row = brow * 128 + wr + i * 16 + g * 4;
#pragma unroll
        for (int r = 0; r < 4; ++r)
          O[(size_t)(row + r) * KDIM + col] = f2b((acc[i][j][r] + bsv) * scz);
      }
    }
  } else {
#pragma unroll
    for (int j = 0; j < 4; ++j) {
      int col = bcol * 128 + wc + j * 16 + li;
      float bsv = bz[col];
#pragma unroll
      for (int i = 0; i < 4; ++i) {
        int row = brow * 128 + wr + i * 16 + g * 4;
#pragma unroll
        for (int r = 0; r < 4; ++r)
          if (row + r < guard)
            outf[(size_t)(row + r) * KDIM + col] = acc[i][j][r] + bsv;
      }
    }
  }
}

// ---------------- fused 5-mask attention -------------------------------------
// Grid (4,12,32); block = 4 waves, wave w owns row-tile rt = bx*4+w (valid<=12).
// Swapped QK^T: lane holds the full score row for query i = rt*16 + (lane&15).
// K staged cooperatively in XOR-swizzled LDS, prefetched one mask ahead.
__global__ __launch_bounds__(256, 2) void k_attn(const u16* __restrict__ qkv,
                                                 u16* __restrict__ att) {
  __shared__ u16 KL[208 * 64];      // swizzled: byte ^= (row&7)<<4   (26.0 KB)
  __shared__ u16 VT[64][232];       // V^T, pad cols zeroed           (29.0 KB)
  __shared__ u16 P[4][16][40];      // per-wave per-kt P chunk        ( 5.0 KB)
  const int tid = threadIdx.x;
  const int w = tid >> 6, lane = tid & 63;
  const int li = lane & 15, g = lane >> 4;
  const int rt = blockIdx.x * 4 + w;
  const int h = blockIdx.y, b = blockIdx.z;
  const size_t rowbase = (size_t)b * 197;
  const int cb = h * 64;
  const u16* Q = qkv;
  const u16* V = qkv + 6 * SLOT;
  const bool task = (rt <= 12);

  // stage V^T (coalesced global reads; cols >=197 zero)
  for (int e = tid; e < 64 * 232; e += 256) {
    int j = e >> 6, d = e & 63;
    u16 val = 0;
    if (j < 197) val = V[(rowbase + j) * KDIM + cb + d];
    VT[d][j] = val;
  }

  // per-lane i-side mask state (constant per task)
  const int i_ = rt * 16 + li;
  const int pi = i_ - 1;
  const int ri = pi / 14, ci = pi % 14;      // pi=-1 -> ri=0, ci=-1 (overridden)
  const bool i0 = (i_ == 0);

  // j-side per-t starting (rj, cj) — register arrays, constant-indexed
  int cj0[13], rj0[13];
#pragma unroll
  for (int t = 0; t < 13; ++t) {
    int pj = t * 16 + g * 4 - 1;
    rj0[t] = pj / 14; cj0[t] = pj % 14;
  }

  bf16x8 qa0, qa1;
  {
    const size_t qrow = rowbase + (size_t)rt * 16 + li;  // <=6362, in-bounds
    qa0 = *(const bf16x8*)(Q + qrow * KDIM + cb + g * 8);
    qa1 = *(const bf16x8*)(Q + qrow * KDIM + cb + 32 + g * 8);
  }

  f32x4 oacc[4] = {};
  uint4 tmp[7];
  const bool c6ok = (tid < 128);             // 1664 = 208 rows * 8 chunks

  // prefetch mask 0's K tile into registers
  {
    const u16* Kg = qkv + SLOT;
#pragma unroll
    for (int c7 = 0; c7 < 7; ++c7) {
      int c = tid + c7 * 256;
      if (c7 < 6 || c6ok) {
        int row = c >> 3, kg = c & 7;
        tmp[c7] = *(const uint4*)(Kg + (rowbase + row) * KDIM + cb + kg * 8);
      }
    }
  }

#pragma unroll
  for (int m = 0; m < 5; ++m) {
    __syncthreads();                         // prev KL readers done (VT for m=0)
    // regs -> swizzled LDS
#pragma unroll
    for (int c7 = 0; c7 < 7; ++c7) {
      int c = tid + c7 * 256;
      if (c7 < 6 || c6ok) {
        int row = c >> 3, kg = c & 7;
        *(uint4*)((char*)KL + ((row * 128 + kg * 16) ^ ((row & 7) << 4))) = tmp[c7];
      }
    }
    // prefetch next mask's K (hides HBM latency under this mask's compute)
    if (m < 4) {
      const u16* Kg = qkv + (size_t)(2 + m) * SLOT;
#pragma unroll
      for (int c7 = 0; c7 < 7; ++c7) {
        int c = tid + c7 * 256;
        if (c7 < 6 || c6ok) {
          int row = c >> 3, kg = c & 7;
          tmp[c7] = *(const uint4*)(Kg + (rowbase + row) * KDIM + cb + kg * 8);
        }
      }
    }
    __syncthreads();

    if (task) {
      // QK^T from LDS, swapped operands: s[t] holds S^T[j][i=li]
      f32x4 s[13];
#pragma unroll
      for (int t = 0; t < 13; ++t) {
        const char* base = (const char*)KL + (size_t)(t * 16 + li) * 128;
        const int sw = (li & 7) << 4;
        bf16x8 kb0 = *(const bf16x8*)(base + ((g * 16) ^ sw));
        bf16x8 kb1 = *(const bf16x8*)(base + ((64 + g * 16) ^ sw));
        f32x4 zz = {};
        zz = __builtin_amdgcn_mfma_f32_16x16x32_bf16(kb0, qa0, zz, 0, 0, 0);
        zz = __builtin_amdgcn_mfma_f32_16x16x32_bf16(kb1, qa1, zz, 0, 0, 0);
        s[t] = zz;
      }
      // analytic mask (log2 domain) + lane-local max
      float mx = -3.0e38f;
#pragma unroll
      for (int t = 0; t < 13; ++t) {
        int jv = t * 16 + g * 4;
        int cjr = cj0[t], rjr = rj0[t];
#pragma unroll
        for (int r = 0; r < 4; ++r) {
          bool mk;
          if (m == 0)      mk = ci < cjr;    // left
          else if (m == 1) mk = ci > cjr;    // right
          else if (m == 2) mk = ri < rjr;    // up
          else if (m == 3) mk = ri > rjr;    // down
          else             mk = (i_ == jv);  // ident
          if (i0 | (jv == 0)) mk = false;    // CLS row/col: uniform -BIG shift
          float sv = s[t][r] - (mk ? 0.f : BIGL);
          if (jv >= 197) sv = -3.0e38f;      // pad cols: hard kill (NaN-safe)
          s[t][r] = sv;
          mx = fmaxf(mx, sv);
          ++jv; ++cjr; if (cjr == 14) { cjr = 0; ++rjr; }
        }
      }
      mx = fmaxf(mx, __shfl_xor(mx, 16));
      mx = fmaxf(mx, __shfl_xor(mx, 32));
      float sum = 0.f;
#pragma unroll
      for (int t = 0; t < 13; ++t)
#pragma unroll
        for (int r = 0; r < 4; ++r) {
          float e_ = exp2f(s[t][r] - mx);
          s[t][r] = e_;
          sum += e_;
        }
      sum += __shfl_xor(sum, 16);
      sum += __shfl_xor(sum, 32);
      const float inv = 1.0f / sum;

      // PV: per-kt pack -> ds_write_b64 -> same-wave ds_read_b128 -> MFMA
#pragma unroll
      for (int kt = 0; kt < 7; ++kt) {
#pragma unroll
        for (int h2 = 0; h2 < 2; ++h2) {
          const int t = kt * 2 + h2;
          uint32_t w0 = 0, w1 = 0;
          if (t < 13) {
            float a0 = s[t][0] * inv, a1 = s[t][1] * inv;
            float a2 = s[t][2] * inv, a3 = s[t][3] * inv;
            asm("v_cvt_pk_bf16_f32 %0, %1, %2" : "=v"(w0) : "v"(a0), "v"(a1));
            asm("v_cvt_pk_bf16_f32 %0, %1, %2" : "=v"(w1) : "v"(a2), "v"(a3));
          }
          uint2 pw; pw.x = w0; pw.y = w1;
          *(uint2*)&P[w][li][h2 * 16 + g * 4] = pw;
        }
        bf16x8 pa = *(const bf16x8*)&P[w][li][g * 8];
#pragma unroll
        for (int dt = 0; dt < 4; ++dt) {
          bf16x8 vb = *(const bf16x8*)&VT[dt * 16 + li][kt * 32 + g * 8];
          oacc[dt] = __builtin_amdgcn_mfma_f32_16x16x32_bf16(pa, vb, oacc[dt],
                                                             0, 0, 0);
        }
      }
    }
  }

  if (task) {
#pragma unroll
    for (int dt = 0; dt < 4; ++dt)
#pragma unroll
      for (int r = 0; r < 4; ++r) {
        int i2 = rt * 16 + g * 4 + r;
        if (i2 < 197)
          att[(rowbase + i2) * KDIM + cb + dt * 16 + li] = f2b(oacc[dt][r]);
      }
  }
}

// -----------------------------------------------------------------------------
extern "C" void kernel_launch(void* const* d_in, const int* in_sizes, int n_in,
                              void* d_out, int out_size, void* d_ws, size_t ws_size,
                              hipStream_t stream) {
  (void)in_sizes; (void)n_in; (void)out_size; (void)ws_size;
  const float* x      = (const float*)d_in[0];
  const float* q_w    = (const float*)d_in[1];
  const float* q_b    = (const float*)d_in[2];
  const float* kA_w   = (const float*)d_in[3];
  const float* kA_b   = (const float*)d_in[4];
  const float* kB_w   = (const float*)d_in[5];
  const float* kB_b   = (const float*)d_in[6];
  const float* kC_w   = (const float*)d_in[7];
  const float* kC_b   = (const float*)d_in[8];
  const float* kD_w   = (const float*)d_in[9];
  const float* kD_b   = (const float*)d_in[10];
  const float* kE_w   = (const float*)d_in[11];
  const float* kE_b   = (const float*)d_in[12];
  const float* v_w    = (const float*)d_in[13];
  const float* v_b    = (const float*)d_in[14];
  const float* proj_w = (const float*)d_in[15];
  const float* proj_b = (const float*)d_in[16];
  float* out = (float*)d_out;

  u16* xb   = (u16*)d_ws;                 // SLOT
  u16* qkv  = xb + SLOT;                  // 7 * SLOT
  u16* wall = qkv + 7 * SLOT;             // 8 * WSZ
  u16* att  = xb;                         // reuse after gemm1 consumed x_b

  Ptr9 cs;
  cs.p[0] = x;    cs.p[1] = q_w;  cs.p[2] = kA_w; cs.p[3] = kB_w;
  cs.p[4] = kC_w; cs.p[5] = kD_w; cs.p[6] = kE_w; cs.p[7] = v_w;
  cs.p[8] = proj_w;
  k_convert<<<dim3(2048), dim3(256), 0, stream>>>(cs, xb, wall);

  Ptr7 b1;
  b1.p[0] = q_b;  b1.p[1] = kA_b; b1.p[2] = kB_b; b1.p[3] = kC_b;
  b1.p[4] = kD_b; b1.p[5] = kE_b; b1.p[6] = v_b;
  k_gemm<<<dim3(50, 6, 7), dim3(256), 0, stream>>>(xb, wall, b1, qkv, nullptr,
                                                   QSCALE_L, 0);

  k_attn<<<dim3(4, 12, 32), dim3(256), 0, stream>>>(qkv, att);

  Ptr7 b2;
  for (int i = 0; i < 7; ++i) b2.p[i] = proj_b;
  k_gemm<<<dim3(50, 6, 1), dim3(256), 0, stream>>>(att, wall + 7 * WSZ, b2,
                                                   nullptr, out, 1.0f, MREAL);
}